// Round 5
// baseline (66092.072 us; speedup 1.0000x reference)
//
#include <hip/hip_runtime.h>
#include <math.h>

// ---------------------------------------------------------------------------
// SimAM-CNN + Mogrifier-LSTM (Round 7): XCD-partitioned persistent LSTM,
// f16 weights + proven barrier primitives + conflict-free high-reuse tiles.
// Round-6 failed (compile or hang) on its ONE unproven primitive: the
// inline-asm sc0-load spin. Round-7 reverts signaling to the round-4-proven
// agent-scope {fetch_add arrive, store release, relaxed-load spin} while
// keeping the round-5-proven MODE-0 data path (plain L2 st/ld + buffer_inv
// acquire, XCD-local groups) and round-6's f16 + tiling payload.
// ---------------------------------------------------------------------------

typedef unsigned short u16;
typedef _Float16 f16;

#define EPSBN 1e-5f

__device__ __forceinline__ float sigf(float x) { return 1.0f / (1.0f + expf(-x)); }

__device__ __forceinline__ float b2f(u16 u) {
  union { unsigned int i; float f; } v; v.i = ((unsigned int)u) << 16; return v.f;
}
__device__ __forceinline__ u16 f2b(float f) {
  union { float f; unsigned int i; } v; v.f = f;
  unsigned int r = v.i + 0x7FFFu + ((v.i >> 16) & 1u);
  return (u16)(r >> 16);
}

template <typename T> __device__ __forceinline__ float ld1(const T* p);
template <> __device__ __forceinline__ float ld1<float>(const float* p) { return *p; }
template <> __device__ __forceinline__ float ld1<u16>(const u16* p) { return b2f(*p); }
template <typename T> __device__ __forceinline__ void st1(T* p, float v);
template <> __device__ __forceinline__ void st1<float>(float* p, float v) { *p = v; }
template <> __device__ __forceinline__ void st1<u16>(u16* p, float v) { *p = f2b(v); }

__device__ __forceinline__ void ldh8(const f16* p, float* w) {
  union { uint4 u; f16 h[8]; } v; v.u = *(const uint4*)p;
#pragma unroll
  for (int i = 0; i < 8; ++i) w[i] = (float)v.h[i];
}
__device__ __forceinline__ void ldh4(const f16* p, float* w) {
  union { uint2 u; f16 h[4]; } v; v.u = *(const uint2*)p;
#pragma unroll
  for (int i = 0; i < 4; ++i) w[i] = (float)v.h[i];
}

// ---- access policies: MODE 0 = plain (same-XCD L2 + L1-inv at barrier);
//      MODE 1 = sc1 agent-scope (device coherence point; fallback).
template <int MODE> struct Acc;
template <> struct Acc<0> {
  static __device__ __forceinline__ float ld(const float* p) { return *p; }
  static __device__ __forceinline__ float4 ld4(const float* p) {
    return *(const float4*)p;
  }
  static __device__ __forceinline__ void st(float* p, float v) { *p = v; }
};
template <> struct Acc<1> {
  static __device__ __forceinline__ float ld(const float* p) {
    return __hip_atomic_load(p, __ATOMIC_RELAXED, __HIP_MEMORY_SCOPE_AGENT);
  }
  static __device__ __forceinline__ float4 ld4(const float* p) {
    union { unsigned long long u[2]; float4 f; } r;
    const unsigned long long* q = (const unsigned long long*)p;
    r.u[0] = __hip_atomic_load(q, __ATOMIC_RELAXED, __HIP_MEMORY_SCOPE_AGENT);
    r.u[1] = __hip_atomic_load(q + 1, __ATOMIC_RELAXED, __HIP_MEMORY_SCOPE_AGENT);
    return r.f;
  }
  static __device__ __forceinline__ void st(float* p, float v) {
    __hip_atomic_store(p, v, __ATOMIC_RELAXED, __HIP_MEMORY_SCOPE_AGENT);
  }
};

__device__ __forceinline__ float simam_elem(float xv, float s, float ss) {
  float mu = (s - xv) * (1.0f / 8191.0f);
  float var = (ss - xv * xv - 8191.0f * mu * mu) * (1.0f / 8190.0f);
  float einv = ((xv - mu) * (xv - mu) + 2.0f * var + 0.2f) / (4.0f * (var + 0.1f));
  return xv * sigf(einv);
}

// --------------------------- CNN stage 1 -----------------------------------
__global__ __launch_bounds__(256) void k_conv1(
    const float* __restrict__ x,
    const float* __restrict__ w1a, const float* __restrict__ b1a,
    const float* __restrict__ g1a, const float* __restrict__ bb1a,
    const float* __restrict__ m1a, const float* __restrict__ v1a,
    const float* __restrict__ w1b, const float* __restrict__ b1b,
    const float* __restrict__ g1b, const float* __restrict__ bb1b,
    const float* __restrict__ m1b, const float* __restrict__ v1b,
    u16* __restrict__ y1u, float* __restrict__ ps1, float* __restrict__ pss1)
{
  __shared__ float xs[6][66];
  __shared__ float a1[32][6][66];
  __shared__ float A1[32], T1[32], S2[32], T2[32];
  __shared__ float reds[4][32], redq[4][32];
  const int tid = threadIdx.x;
  const int b = blockIdx.x, t0 = blockIdx.y * 4;
  if (tid < 32) {
    float s = g1a[tid] * rsqrtf(v1a[tid] + EPSBN);
    A1[tid] = w1a[tid] * s;
    T1[tid] = (b1a[tid] - m1a[tid]) * s + bb1a[tid];
    float s2 = g1b[tid] * rsqrtf(v1b[tid] + EPSBN);
    S2[tid] = s2;
    T2[tid] = (b1b[tid] - m1b[tid]) * s2 + bb1b[tid];
  }
  for (int i = tid; i < 6 * 66; i += 256) {
    int r = i / 66, cc = i - r * 66;
    int t = t0 + r - 1, d = cc - 1;
    float v = 0.f;
    if (t >= 0 && t < 128 && d >= 0 && d < 64) v = x[(b * 128 + t) * 64 + d];
    xs[r][cc] = v;
  }
  __syncthreads();
  for (int i = tid; i < 32 * 6 * 66; i += 256) {
    int c = i / 396;
    int rr = i - c * 396;
    int r = rr / 66, cc = rr - r * 66;
    int t = t0 + r - 1, d = cc - 1;
    float v = 0.f;
    if (t >= 0 && t < 128 && d >= 0 && d < 64)
      v = fmaxf(xs[r][cc] * A1[c] + T1[c], 0.f);
    a1[c][r][cc] = v;
  }
  __syncthreads();
  const int d = tid & 63, tq = tid >> 6, lane = tid & 63;
  float acc[32];
#pragma unroll
  for (int i = 0; i < 32; ++i) acc[i] = 0.f;
#pragma unroll 1
  for (int c1 = 0; c1 < 32; ++c1) {
#pragma unroll
    for (int dt = 0; dt < 3; ++dt) {
      float av0 = a1[c1][tq + dt][d];
      float av1 = a1[c1][tq + dt][d + 1];
      float av2 = a1[c1][tq + dt][d + 2];
#pragma unroll
      for (int c2 = 0; c2 < 32; ++c2) {
        const float* wp = w1b + ((c2 * 32 + c1) * 3 + dt) * 3;  // uniform
        acc[c2] += av0 * wp[0] + av1 * wp[1] + av2 * wp[2];
      }
    }
  }
  const size_t ob = (size_t)b * 32 * 8192 + (size_t)(t0 + tq) * 64 + d;
#pragma unroll
  for (int c2 = 0; c2 < 32; ++c2) {
    float v = fmaxf(acc[c2] * S2[c2] + T2[c2], 0.f);
    y1u[ob + (size_t)c2 * 8192] = f2b(v);
    float s = v, q = v * v;
#pragma unroll
    for (int off = 32; off; off >>= 1) {
      s += __shfl_down(s, off);
      q += __shfl_down(q, off);
    }
    if (lane == 0) { reds[tq][c2] = s; redq[tq][c2] = q; }
  }
  __syncthreads();
  if (tid < 32) {
    float s = (reds[0][tid] + reds[1][tid]) + (reds[2][tid] + reds[3][tid]);
    float q = (redq[0][tid] + redq[1][tid]) + (redq[2][tid] + redq[3][tid]);
    ps1[(size_t)((b * 32 + tid) << 5) + blockIdx.y] = s;
    pss1[(size_t)((b * 32 + tid) << 5) + blockIdx.y] = q;
  }
}

__global__ __launch_bounds__(256) void k_red(
    const float* __restrict__ ps, const float* __restrict__ pss,
    float* __restrict__ stats, int npart, int nplanes)
{
  int p = blockIdx.x * 256 + threadIdx.x;
  if (p >= nplanes) return;
  float s = 0.f, q = 0.f;
  for (int j = 0; j < npart; ++j) {
    s += ps[(size_t)p * npart + j];
    q += pss[(size_t)p * npart + j];
  }
  stats[p] = s;
  stats[nplanes + p] = q;
}

template <typename T>
__global__ __launch_bounds__(256) void k_simam_t(
    T* __restrict__ buf, const float* __restrict__ stats, int nplanes)
{
  const int p = blockIdx.x, tid = threadIdx.x;
  T* base = buf + (size_t)p * 8192;
  const float s = stats[p], ss = stats[nplanes + p];
#pragma unroll 4
  for (int i = 0; i < 32; ++i) {
    int idx = tid + i * 256;
    float v = ld1(base + idx);
    st1(base + idx, simam_elem(v, s, ss));
  }
}

// --------------------------- CNN stage 2 -----------------------------------
template <typename ZT>
__global__ __launch_bounds__(256) void k_conv2(
    const u16* __restrict__ y1u,
    const float* __restrict__ w2a, const float* __restrict__ b2a,
    const float* __restrict__ g2a, const float* __restrict__ bb2a,
    const float* __restrict__ m2a, const float* __restrict__ v2a,
    const float* __restrict__ w2b, const float* __restrict__ b2b,
    const float* __restrict__ g2b, const float* __restrict__ bb2b,
    const float* __restrict__ m2b, const float* __restrict__ v2b,
    ZT* __restrict__ z, float* __restrict__ ps2, float* __restrict__ pss2)
{
  __shared__ float y1s[32][4][66];
  __shared__ float a2[64][4][66];
  __shared__ float sA2a[64], sT2a[64], sA2b[64], sT2b[64];
  const int tid = threadIdx.x;
  const int t0 = blockIdx.x * 2, b = blockIdx.y;
  if (tid < 64) {
    float sa = g2a[tid] * rsqrtf(v2a[tid] + EPSBN);
    sA2a[tid] = sa;
    sT2a[tid] = (b2a[tid] - m2a[tid]) * sa + bb2a[tid];
    float sb = g2b[tid] * rsqrtf(v2b[tid] + EPSBN);
    sA2b[tid] = sb;
    sT2b[tid] = (b2b[tid] - m2b[tid]) * sb + bb2b[tid];
  }
  for (int i = tid; i < 32 * 4 * 66; i += 256) {
    int c1 = i / 264;
    int rr = i - c1 * 264;
    int r = rr / 66, cc = rr - r * 66;
    int t = t0 + r - 1, dd = cc - 1;
    float v = 0.f;
    if (t >= 0 && t < 128 && dd >= 0 && dd < 64)
      v = b2f(y1u[(size_t)(b * 32 + c1) * 8192 + t * 64 + dd]);
    y1s[c1][r][cc] = v;
  }
  __syncthreads();
  const int lane = tid & 63;
  const int c2base = __builtin_amdgcn_readfirstlane((int)(tid >> 6)) * 16;
#pragma unroll 1
  for (int i = 0; i < 16; ++i) {
    const int c2 = c2base + i;
    const float* wp = w2a + c2 * 32;  // uniform
    const float scl = sA2a[c2], off = sT2a[c2];
#pragma unroll 1
    for (int r = 0; r < 4; ++r) {
      for (int cc = lane; cc < 66; cc += 64) {
        float acc = 0.f;
#pragma unroll
        for (int c1 = 0; c1 < 32; ++c1) acc += y1s[c1][r][cc] * wp[c1];
        int t = t0 + r - 1, dd = cc - 1;
        float val = 0.f;
        if (t >= 0 && t < 128 && dd >= 0 && dd < 64)
          val = fmaxf(acc * scl + off, 0.f);
        a2[c2][r][cc] = val;
      }
    }
  }
  __syncthreads();
  const int d = tid & 63;
  const int gq = __builtin_amdgcn_readfirstlane((int)(tid >> 6));
  float acc[16][2];
#pragma unroll
  for (int i = 0; i < 16; ++i) { acc[i][0] = 0.f; acc[i][1] = 0.f; }
#pragma unroll 1
  for (int c1 = 0; c1 < 64; ++c1) {
    float a00 = a2[c1][0][d], a01 = a2[c1][0][d + 1], a02 = a2[c1][0][d + 2];
    float a10 = a2[c1][1][d], a11 = a2[c1][1][d + 1], a12 = a2[c1][1][d + 2];
    float a20 = a2[c1][2][d], a21 = a2[c1][2][d + 1], a22 = a2[c1][2][d + 2];
    float a30 = a2[c1][3][d], a31 = a2[c1][3][d + 1], a32 = a2[c1][3][d + 2];
#pragma unroll
    for (int i = 0; i < 16; ++i) {
      const float* wp = w2b + (size_t)((gq * 16 + i) * 64 + c1) * 9;  // uniform
      float w0 = wp[0], w1 = wp[1], w2 = wp[2];
      float w3 = wp[3], w4 = wp[4], w5 = wp[5];
      float w6 = wp[6], w7 = wp[7], w8 = wp[8];
      acc[i][0] += a00 * w0 + a01 * w1 + a02 * w2 + a10 * w3 + a11 * w4 +
                   a12 * w5 + a20 * w6 + a21 * w7 + a22 * w8;
      acc[i][1] += a10 * w0 + a11 * w1 + a12 * w2 + a20 * w3 + a21 * w4 +
                   a22 * w5 + a30 * w6 + a31 * w7 + a32 * w8;
    }
  }
#pragma unroll
  for (int i = 0; i < 16; ++i) {
    int c2 = gq * 16 + i;
    float sc = sA2b[c2], tb = sT2b[c2];
    float v0 = fmaxf(acc[i][0] * sc + tb, 0.f);
    float v1 = fmaxf(acc[i][1] * sc + tb, 0.f);
    size_t ob = (size_t)(b * 64 + c2) * 8192 + (size_t)t0 * 64 + d;
    st1(z + ob, v0);
    st1(z + ob + 64, v1);
    float s = v0 + v1, q = v0 * v0 + v1 * v1;
#pragma unroll
    for (int off = 32; off; off >>= 1) {
      s += __shfl_down(s, off);
      q += __shfl_down(q, off);
    }
    if (lane == 0) {
      ps2[(size_t)((b * 64 + c2) << 6) + blockIdx.x] = s;
      pss2[(size_t)((b * 64 + c2) << 6) + blockIdx.x] = q;
    }
  }
}

// --------------------- weight conversion (f32 -> f16) ----------------------
__global__ __launch_bounds__(256) void k_w16(const float* __restrict__ s,
                                             f16* __restrict__ d, int n) {
  for (int i = blockIdx.x * 256 + threadIdx.x; i < n; i += gridDim.x * 256)
    d[i] = (f16)s[i];
}
// split-pair shuffle within S-chunks: dst[base + ln*8 + j] = src[base + k],
// k = j<4 ? ln*4+j : S/2 + ln*4 + (j-4). Makes each lane's 8 halves one
// contiguous 16B load while LDS activation reads stay bank-conflict-free.
__global__ __launch_bounds__(256) void k_w16sh(const float* __restrict__ s,
                                               f16* __restrict__ d, int n,
                                               int lgS) {
  const int S = 1 << lgS, half = S >> 1;
  for (int i = blockIdx.x * 256 + threadIdx.x; i < n; i += gridDim.x * 256) {
    int q = i & (S - 1);
    int base = i - q;
    int ln = q >> 3, j = q & 7;
    int ks = (j < 4) ? (ln * 4 + j) : (half + ln * 4 + (j - 4));
    d[i] = (f16)s[base + ks];
  }
}

// --------------------------- persistent LSTM -------------------------------
struct LPar {
  const void* z;
  const f16 *qw0, *qw1, *qw2, *rw0, *rw1, *rw2, *wih, *whh;
  const float *qb0, *qb1, *qb2, *rb0, *rb1, *rb2;
  const float *bih, *bhh, *fcw, *fcb;
  float* grp;     // 8 groups x 131072 floats
  unsigned* bar;  // barrier / rendezvous state
  float* out;
};

#define BAR_XCNT 1024
#define BAR_LIN  1280
#define BAR_RCNT 1312
#define BAR_RREL 1344

// device-wide rendezvous (agent scope, one-shot) — round-4-proven pattern.
__device__ __forceinline__ void devbar(unsigned* cnt, unsigned* rel) {
  __syncthreads();
  if (threadIdx.x == 0) {
    unsigned prev = __hip_atomic_fetch_add(cnt, 1u, __ATOMIC_RELAXED,
                                           __HIP_MEMORY_SCOPE_AGENT);
    if (prev == 255u)
      __hip_atomic_store(rel, 1u, __ATOMIC_RELAXED, __HIP_MEMORY_SCOPE_AGENT);
    while (__hip_atomic_load(rel, __ATOMIC_RELAXED,
                             __HIP_MEMORY_SCOPE_AGENT) == 0u)
      __builtin_amdgcn_s_sleep(2);
  }
  __syncthreads();
  asm volatile("" ::: "memory");
}

// intra-group barrier (32 blocks of one XCD).
// Signaling (both modes): agent-scope fetch_add arrive + agent store release
// + agent relaxed-load spin — each primitive proven on HW in round 4.
// MODE 0 acquire: buffer_inv (per-CU L1 invalidate, round-5-proven) so plain
// loads after the barrier see the other blocks' L2-resident stores.
template <int MODE>
__device__ __forceinline__ void grpbar(unsigned* cnt, unsigned* rel,
                                       unsigned gen) {
  __syncthreads();
  if (threadIdx.x == 0) {
    unsigned prev = __hip_atomic_fetch_add(cnt, 1u, __ATOMIC_RELAXED,
                                           __HIP_MEMORY_SCOPE_AGENT);
    if (prev == gen * 32u - 1u)
      __hip_atomic_store(rel, gen, __ATOMIC_RELAXED,
                         __HIP_MEMORY_SCOPE_AGENT);
    while (__hip_atomic_load(rel, __ATOMIC_RELAXED,
                             __HIP_MEMORY_SCOPE_AGENT) < gen)
      __builtin_amdgcn_s_sleep(1);
    if (MODE == 0)
      asm volatile("buffer_inv\n\ts_waitcnt vmcnt(0)" ::: "memory");
  }
  __syncthreads();
  asm volatile("" ::: "memory");
}

// fill h_lds[16][260] from a global [16][256] buffer (1024 thr, 1 float4 ea)
template <int MODE>
__device__ __forceinline__ void fill_h(float* h_lds, const float* src,
                                       const int tid) {
  const int r = tid >> 6, c4 = (tid & 63) * 4;
  float4 v = Acc<MODE>::ld4(src + r * 256 + c4);
  *(float4*)&h_lds[r * 260 + c4] = v;
}

// q stage: xm[r][n] = 2*sig(hm . qW[n] + qb[n]) * xsrc; K=256.
// Thread org: sub=tid&7 (8-way k-split), grp=tid>>3: ngrp=grp&31 (4 n),
// rgrp=grp>>5 (4 rows). Weights pre-shuffled with S=64.
template <typename ZT, int MODE>
__device__ __forceinline__ void q_stage(
    const f16* qW, const float* qb, const int sflag, const int t,
    const ZT* zz, float* xm, const float* h_lds, float* red, const int rank,
    const int row0, const int tid)
{
  using A = Acc<MODE>;
  const int sub = tid & 7, grp = tid >> 3;
  const int ngrp = grp & 31, rgrp = grp >> 5;
  const int n0 = ngrp * 4, r0 = rgrp * 4;
  const f16* wbase = qW + (size_t)(rank * 128 + n0) * 256;
  float acc[4][4];
#pragma unroll
  for (int j = 0; j < 4; ++j)
#pragma unroll
    for (int rr = 0; rr < 4; ++rr) acc[j][rr] = 0.f;
#pragma unroll
  for (int it = 0; it < 4; ++it) {
    const int koff = it * 64 + sub * 8;
    const int ka = it * 64 + sub * 4, kb = ka + 32;
    float x[4][8];
#pragma unroll
    for (int rr = 0; rr < 4; ++rr) {
      *(float4*)&x[rr][0] = *(const float4*)&h_lds[(r0 + rr) * 260 + ka];
      *(float4*)&x[rr][4] = *(const float4*)&h_lds[(r0 + rr) * 260 + kb];
    }
#pragma unroll
    for (int j = 0; j < 4; ++j) {
      float w[8];
      ldh8(wbase + (size_t)j * 256 + koff, w);
#pragma unroll
      for (int rr = 0; rr < 4; ++rr)
        acc[j][rr] += w[0]*x[rr][0] + w[1]*x[rr][1] + w[2]*x[rr][2] +
                      w[3]*x[rr][3] + w[4]*x[rr][4] + w[5]*x[rr][5] +
                      w[6]*x[rr][6] + w[7]*x[rr][7];
    }
  }
#pragma unroll
  for (int j = 0; j < 4; ++j)
#pragma unroll
    for (int rr = 0; rr < 4; ++rr) {
      float v = acc[j][rr];
      v += __shfl_xor(v, 4); v += __shfl_xor(v, 2); v += __shfl_xor(v, 1);
      acc[j][rr] = v;
    }
  if (sub == 0) {
#pragma unroll
    for (int j = 0; j < 4; ++j)
#pragma unroll
      for (int rr = 0; rr < 4; ++rr)
        red[(n0 + j) * 17 + r0 + rr] = acc[j][rr];
  }
  __syncthreads();
#pragma unroll
  for (int hh = 0; hh < 2; ++hh) {
    const int idx = tid + hh * 1024;
    const int nl = idx & 127, r = idx >> 7;
    const int n = rank * 128 + nl;
    float s = red[nl * 17 + r] + qb[n];
    float xv;
    if (sflag == 0)
      xv = ld1(zz + (size_t)(row0 + r) * 524288 + (size_t)t * 4096 + n);
    else
      xv = A::ld(xm + (size_t)r * 4096 + n);
    A::st(xm + (size_t)r * 4096 + n, 2.0f * sigf(s) * xv);
  }
  __syncthreads();
}

// r stage: hm_out[r][n] = 2*sig(xm[r].rW[n] + rb[n]) * src[r][n]; K=4096.
// Wave wv: np=wv&3 (2 n), rgrp=wv>>2 (4 rows); lane 64-way k-split.
template <int MODE>
__device__ __forceinline__ void r_stage(
    const f16* rW, const float* rb, float* hm_out, const float* xm,
    const float* h_lds, float* xm_lds, float* red, const int rank,
    const int tid, const int wv, const int ln)
{
  using A = Acc<MODE>;
  const int np = wv & 3, rgrp = wv >> 2;
  const int r0 = rgrp * 4;
  const f16* w0 = rW + (size_t)(rank * 8 + np * 2) * 4096;
  const f16* w1 = w0 + 4096;
  float acc[2][4];
#pragma unroll
  for (int j = 0; j < 2; ++j)
#pragma unroll
    for (int rr = 0; rr < 4; ++rr) acc[j][rr] = 0.f;
#pragma unroll 1
  for (int sl = 0; sl < 4; ++sl) {
    __syncthreads();
#pragma unroll
    for (int j = 0; j < 4; ++j) {
      const int f = tid + j * 1024;
      const int row = f >> 8, col = (f & 255) * 4;
      float4 v = A::ld4(xm + (size_t)row * 4096 + sl * 1024 + col);
      *(float4*)&xm_lds[row * 1032 + col] = v;
    }
    __syncthreads();
#pragma unroll
    for (int it = 0; it < 2; ++it) {
      const int ka = it * 512 + ln * 4, kb = ka + 256;
      const int koff = sl * 1024 + it * 512 + ln * 8;
      float x[4][8];
#pragma unroll
      for (int rr = 0; rr < 4; ++rr) {
        *(float4*)&x[rr][0] = *(const float4*)&xm_lds[(r0 + rr) * 1032 + ka];
        *(float4*)&x[rr][4] = *(const float4*)&xm_lds[(r0 + rr) * 1032 + kb];
      }
      float w[8];
      ldh8(w0 + koff, w);
#pragma unroll
      for (int rr = 0; rr < 4; ++rr)
        acc[0][rr] += w[0]*x[rr][0] + w[1]*x[rr][1] + w[2]*x[rr][2] +
                      w[3]*x[rr][3] + w[4]*x[rr][4] + w[5]*x[rr][5] +
                      w[6]*x[rr][6] + w[7]*x[rr][7];
      ldh8(w1 + koff, w);
#pragma unroll
      for (int rr = 0; rr < 4; ++rr)
        acc[1][rr] += w[0]*x[rr][0] + w[1]*x[rr][1] + w[2]*x[rr][2] +
                      w[3]*x[rr][3] + w[4]*x[rr][4] + w[5]*x[rr][5] +
                      w[6]*x[rr][6] + w[7]*x[rr][7];
    }
  }
#pragma unroll
  for (int j = 0; j < 2; ++j)
#pragma unroll
    for (int rr = 0; rr < 4; ++rr) {
      float v = acc[j][rr];
#pragma unroll
      for (int m = 32; m; m >>= 1) v += __shfl_xor(v, m);
      acc[j][rr] = v;
    }
  if (ln == 0) {
#pragma unroll
    for (int j = 0; j < 2; ++j)
#pragma unroll
      for (int rr = 0; rr < 4; ++rr)
        red[(np * 2 + j) * 17 + r0 + rr] = acc[j][rr];
  }
  __syncthreads();
  if (tid < 128) {
    const int nj = tid >> 4, r = tid & 15;
    const int n = rank * 8 + nj;
    float s = red[nj * 17 + r] + rb[n];
    A::st(hm_out + (size_t)r * 256 + n, 2.0f * sigf(s) * h_lds[r * 260 + n]);
  }
  __syncthreads();
}

// gates stage: gates[r][nj] = xm[r].wih[nj] + hm2[r].whh[nj]; nj slice of 32.
// Wave wv: ggrp=wv&3 (8 gate rows), rgrp=wv>>2 (4 rows); 64-way k-split.
template <int MODE>
__device__ __forceinline__ void g_stage(
    const f16* wih, const f16* whh, float* gates, const float* xm,
    const float* h_lds, float* xm_lds, float* red, const int rank,
    const int tid, const int wv, const int ln)
{
  using A = Acc<MODE>;
  const int ggrp = wv & 3, rgrp = wv >> 2;
  const int r0 = rgrp * 4, gj0 = ggrp * 8;
  const f16* wb = wih + (size_t)(rank * 32 + gj0) * 4096;
  float acc[8][4];
#pragma unroll
  for (int j = 0; j < 8; ++j)
#pragma unroll
    for (int rr = 0; rr < 4; ++rr) acc[j][rr] = 0.f;
#pragma unroll 1
  for (int sl = 0; sl < 4; ++sl) {
    __syncthreads();
#pragma unroll
    for (int j = 0; j < 4; ++j) {
      const int f = tid + j * 1024;
      const int row = f >> 8, col = (f & 255) * 4;
      float4 v = A::ld4(xm + (size_t)row * 4096 + sl * 1024 + col);
      *(float4*)&xm_lds[row * 1032 + col] = v;
    }
    __syncthreads();
#pragma unroll
    for (int it = 0; it < 2; ++it) {
      const int ka = it * 512 + ln * 4, kb = ka + 256;
      const int koff = sl * 1024 + it * 512 + ln * 8;
      float x[4][8];
#pragma unroll
      for (int rr = 0; rr < 4; ++rr) {
        *(float4*)&x[rr][0] = *(const float4*)&xm_lds[(r0 + rr) * 1032 + ka];
        *(float4*)&x[rr][4] = *(const float4*)&xm_lds[(r0 + rr) * 1032 + kb];
      }
#pragma unroll
      for (int j = 0; j < 8; ++j) {
        float w[8];
        ldh8(wb + (size_t)j * 4096 + koff, w);
#pragma unroll
        for (int rr = 0; rr < 4; ++rr)
          acc[j][rr] += w[0]*x[rr][0] + w[1]*x[rr][1] + w[2]*x[rr][2] +
                        w[3]*x[rr][3] + w[4]*x[rr][4] + w[5]*x[rr][5] +
                        w[6]*x[rr][6] + w[7]*x[rr][7];
      }
    }
  }
  {  // whh part: K=256, lane chunk = 4 halves (linear layout)
    const f16* wh = whh + (size_t)(rank * 32 + gj0) * 256;
    float x[4][4];
#pragma unroll
    for (int rr = 0; rr < 4; ++rr)
      *(float4*)&x[rr][0] = *(const float4*)&h_lds[(r0 + rr) * 260 + ln * 4];
#pragma unroll
    for (int j = 0; j < 8; ++j) {
      float w[4];
      ldh4(wh + (size_t)j * 256 + ln * 4, w);
#pragma unroll
      for (int rr = 0; rr < 4; ++rr)
        acc[j][rr] += w[0]*x[rr][0] + w[1]*x[rr][1] + w[2]*x[rr][2] +
                      w[3]*x[rr][3];
    }
  }
#pragma unroll
  for (int j = 0; j < 8; ++j)
#pragma unroll
    for (int rr = 0; rr < 4; ++rr) {
      float v = acc[j][rr];
#pragma unroll
      for (int m = 32; m; m >>= 1) v += __shfl_xor(v, m);
      acc[j][rr] = v;
    }
  if (ln == 0) {
#pragma unroll
    for (int j = 0; j < 8; ++j)
#pragma unroll
      for (int rr = 0; rr < 4; ++rr)
        red[(gj0 + j) * 17 + r0 + rr] = acc[j][rr];
  }
  __syncthreads();
  if (tid < 512) {
    const int gj = tid >> 4, r = tid & 15;
    A::st(gates + (size_t)r * 1024 + rank * 32 + gj, red[gj * 17 + r]);
  }
  __syncthreads();
}

template <typename ZT, int MODE>
__device__ void lstm_body(const LPar& p, const int grpi, const int rank,
                          float* h_lds, float* c_lds, float* xm_lds,
                          float* red)
{
  using A = Acc<MODE>;
  float* gb    = p.grp + (size_t)grpi * 131072;
  float* xm    = gb;
  float* hmA   = gb + 65536;
  float* hmB   = gb + 69632;
  float* hmC   = gb + 73728;
  float* gates = gb + 77824;
  unsigned* bcnt = p.bar + (MODE == 0 ? 0 : 512) + grpi * 64;
  unsigned* brel = bcnt + 32;
  const int tid = threadIdx.x;
  const int wv = tid >> 6, ln = tid & 63;
  const int row0 = grpi * 16;
  const ZT* zz = (const ZT*)p.z;
  unsigned gen = 0;

  for (int t = 0; t <= 128; ++t) {
    // ---- hfin (computed redundantly by every block; h,c in LDS) ----
    if (t == 0) {
      for (int j = tid; j < 4096; j += 1024) {
        h_lds[(j >> 8) * 260 + (j & 255)] = 0.f;
        c_lds[j] = 0.f;
      }
    } else {
      for (int j = tid; j < 4096; j += 1024) {
        const int r = j >> 8, k = j & 255;
        const float* gr = gates + r * 1024 + k;
        float gi = A::ld(gr)       + p.bih[k]       + p.bhh[k];
        float gf = A::ld(gr + 256) + p.bih[k + 256] + p.bhh[k + 256];
        float gg = A::ld(gr + 512) + p.bih[k + 512] + p.bhh[k + 512];
        float go = A::ld(gr + 768) + p.bih[k + 768] + p.bhh[k + 768];
        float cn = sigf(gf) * c_lds[j] + sigf(gi) * tanhf(gg);
        c_lds[j] = cn;
        h_lds[r * 260 + k] = sigf(go) * tanhf(cn);
      }
    }
    __syncthreads();
    if (t == 128) break;

    // q0 (src=z, hm=h)
    q_stage<ZT, MODE>(p.qw0, p.qb0, 0, t, zz, xm, h_lds, red, rank, row0, tid);
    grpbar<MODE>(bcnt, brel, ++gen);
    // r0 -> hmA (src=h, still in h_lds)
    r_stage<MODE>(p.rw0, p.rb0, hmA, xm, h_lds, xm_lds, red, rank, tid, wv, ln);
    grpbar<MODE>(bcnt, brel, ++gen);
    // q1 (hm=hmA)
    fill_h<MODE>(h_lds, hmA, tid);
    __syncthreads();
    q_stage<ZT, MODE>(p.qw1, p.qb1, 1, t, zz, xm, h_lds, red, rank, row0, tid);
    grpbar<MODE>(bcnt, brel, ++gen);
    // r1 -> hmB (src=hmA)
    r_stage<MODE>(p.rw1, p.rb1, hmB, xm, h_lds, xm_lds, red, rank, tid, wv, ln);
    grpbar<MODE>(bcnt, brel, ++gen);
    // q2 (hm=hmB)
    fill_h<MODE>(h_lds, hmB, tid);
    __syncthreads();
    q_stage<ZT, MODE>(p.qw2, p.qb2, 1, t, zz, xm, h_lds, red, rank, row0, tid);
    grpbar<MODE>(bcnt, brel, ++gen);
    // r2 -> hmC (src=hmB)
    r_stage<MODE>(p.rw2, p.rb2, hmC, xm, h_lds, xm_lds, red, rank, tid, wv, ln);
    grpbar<MODE>(bcnt, brel, ++gen);
    // gates = xm@wih^T + hmC@whh^T
    fill_h<MODE>(h_lds, hmC, tid);
    __syncthreads();
    g_stage<MODE>(p.wih, p.whh, gates, xm, h_lds, xm_lds, red, rank, tid, wv, ln);
    grpbar<MODE>(bcnt, brel, ++gen);
  }
  // ---- FC (rank 0 of each group; h is in LDS) ----
  if (rank == 0 && tid < 80) {
    const int r = tid / 5, j = tid % 5;
    float acc = p.fcb[j];
    const float* w = p.fcw + j * 256;
    const float* hr = &h_lds[r * 260];
    for (int k = 0; k < 256; ++k) acc += hr[k] * w[k];
    p.out[(size_t)(row0 + r) * 5 + j] = acc;
  }
}

// 256 blocks x 1024 threads; ~105KB static LDS forces 1 block/CU, so each
// XCD hosts exactly 32 blocks -> XCD-local groups are complete.
template <typename ZT>
__global__ __launch_bounds__(1024, 4) void k_lstm(LPar p)
{
  __shared__ float h_lds[16 * 260];
  __shared__ float c_lds[4096];
  __shared__ float xm_lds[16 * 1032];
  __shared__ float red[2200];
  __shared__ unsigned s_meta[4];
  const int tid = threadIdx.x;

  if (tid == 0) {
    unsigned xcc;
    asm volatile("s_getreg_b32 %0, hwreg(HW_REG_XCC_ID)" : "=s"(xcc));
    xcc &= 7u;
    unsigned fr = __hip_atomic_fetch_add(p.bar + BAR_XCNT + xcc * 32, 1u,
                                         __ATOMIC_RELAXED,
                                         __HIP_MEMORY_SCOPE_AGENT);
    unsigned lr = __hip_atomic_fetch_add(p.bar + BAR_LIN, 1u,
                                         __ATOMIC_RELAXED,
                                         __HIP_MEMORY_SCOPE_AGENT);
    s_meta[0] = xcc; s_meta[1] = fr; s_meta[2] = lr;
  }
  __syncthreads();
  devbar(p.bar + BAR_RCNT, p.bar + BAR_RREL);
  if (tid == 0) {
    unsigned ok = 1u;
    for (int x = 0; x < 8; ++x)
      ok &= (__hip_atomic_load(p.bar + BAR_XCNT + x * 32, __ATOMIC_RELAXED,
                               __HIP_MEMORY_SCOPE_AGENT) == 32u) ? 1u : 0u;
    s_meta[3] = ok;
  }
  __syncthreads();
  if (s_meta[3]) {
    lstm_body<ZT, 0>(p, (int)s_meta[0], (int)(s_meta[1] & 31u),
                     h_lds, c_lds, xm_lds, red);
  } else {
    lstm_body<ZT, 1>(p, (int)(s_meta[2] >> 5), (int)(s_meta[2] & 31u),
                     h_lds, c_lds, xm_lds, red);
  }
}

// diagnostic: report ws_size (MiB) through the output if workspace too small
__global__ __launch_bounds__(256) void k_report(float* out, float v, int n) {
  int i = blockIdx.x * 256 + threadIdx.x;
  if (i < n) out[i] = v;
}

// ---------------------------------------------------------------------------
struct Net {
  const float *x;
  const float *c1a_w, *c1a_b, *g1a, *b1a, *m1a, *v1a;
  const float *c1b_w, *c1b_b, *g1b, *b1b, *m1b, *v1b;
  const float *c2a_w, *c2a_b, *g2a, *b2a, *m2a, *v2a;
  const float *c2b_w, *c2b_b, *g2b, *b2b, *m2b, *v2b;
  const float *qw[3], *qb[3], *rw[3], *rb[3];
  const float *wih, *whh, *bih, *bhh, *fcw, *fcb;
};

template <typename ZT>
static void run_all(const Net& p, ZT* z, u16* y1u, float* scr,
                    float* ps1, float* pss1, float* st1v,
                    float* ps2, float* pss2, float* st2v,
                    float* out, hipStream_t stream)
{
  float* grp = scr;                               // 8*131072 = 1,048,576 f
  unsigned* bar = (unsigned*)(scr + 1048576);     // 2048 u32 barrier state
  f16* wf = (f16*)(scr + 1050624);                // 10,747,904 halves (~20.5MB)

  k_conv1<<<dim3(128, 32), 256, 0, stream>>>(p.x, p.c1a_w, p.c1a_b, p.g1a,
      p.b1a, p.m1a, p.v1a, p.c1b_w, p.c1b_b, p.g1b, p.b1b, p.m1b, p.v1b,
      y1u, ps1, pss1);
  k_red<<<16, 256, 0, stream>>>(ps1, pss1, st1v, 32, 4096);
  k_simam_t<u16><<<4096, 256, 0, stream>>>(y1u, st1v, 4096);
  k_conv2<ZT><<<dim3(64, 128), 256, 0, stream>>>(y1u, p.c2a_w, p.c2a_b, p.g2a,
      p.b2a, p.m2a, p.v2a, p.c2b_w, p.c2b_b, p.g2b, p.b2b, p.m2b, p.v2b,
      z, ps2, pss2);
  k_red<<<32, 256, 0, stream>>>(ps2, pss2, st2v, 64, 8192);
  k_simam_t<ZT><<<8192, 256, 0, stream>>>(z, st2v, 8192);

  // f16 weight conversion — after the CNN is done with the y1u region
  // (wf/bar live in the y1u overlay). qw/rw/wih use the split-pair shuffle.
  k_w16sh<<<2048, 256, 0, stream>>>(p.qw[0], wf,            1048576, 6);
  k_w16sh<<<2048, 256, 0, stream>>>(p.qw[1], wf + 1048576,  1048576, 6);
  k_w16sh<<<2048, 256, 0, stream>>>(p.qw[2], wf + 2097152,  1048576, 6);
  k_w16sh<<<2048, 256, 0, stream>>>(p.rw[0], wf + 3145728,  1048576, 9);
  k_w16sh<<<2048, 256, 0, stream>>>(p.rw[1], wf + 4194304,  1048576, 9);
  k_w16sh<<<2048, 256, 0, stream>>>(p.rw[2], wf + 5242880,  1048576, 9);
  k_w16sh<<<4096, 256, 0, stream>>>(p.wih,   wf + 6291456,  4194304, 9);
  k_w16  <<<1024, 256, 0, stream>>>(p.whh,   wf + 10485760, 262144);

  hipMemsetAsync((void*)bar, 0, 8192, stream);

  LPar P;
  P.z = (const void*)z;
  P.qw0 = wf;            P.qw1 = wf + 1048576;  P.qw2 = wf + 2097152;
  P.rw0 = wf + 3145728;  P.rw1 = wf + 4194304;  P.rw2 = wf + 5242880;
  P.wih = wf + 6291456;  P.whh = wf + 10485760;
  P.qb0 = p.qb[0]; P.qb1 = p.qb[1]; P.qb2 = p.qb[2];
  P.rb0 = p.rb[0]; P.rb1 = p.rb[1]; P.rb2 = p.rb[2];
  P.bih = p.bih; P.bhh = p.bhh; P.fcw = p.fcw; P.fcb = p.fcb;
  P.grp = grp; P.bar = bar; P.out = out;

  void* args[] = { (void*)&P };
  hipError_t e = hipLaunchCooperativeKernel(
      (const void*)k_lstm<ZT>, dim3(256), dim3(1024), args, 0, stream);
  if (e != hipSuccess) {
    (void)hipGetLastError();  // clear sticky error
    // ~105KB LDS/block => 1 block/CU; 256 blocks on 256 CUs co-resident.
    k_lstm<ZT><<<dim3(256), dim3(1024), 0, stream>>>(P);
  }
}

extern "C" void kernel_launch(void* const* d_in, const int* in_sizes, int n_in,
                              void* d_out, int out_size, void* d_ws, size_t ws_size,
                              hipStream_t stream)
{
  (void)in_sizes; (void)n_in;
  Net p;
  p.x = (const float*)d_in[0];
  p.c1a_w = (const float*)d_in[1];  p.c1a_b = (const float*)d_in[2];
  p.g1a = (const float*)d_in[3];    p.b1a = (const float*)d_in[4];
  p.m1a = (const float*)d_in[5];    p.v1a = (const float*)d_in[6];
  p.c1b_w = (const float*)d_in[7];  p.c1b_b = (const float*)d_in[8];
  p.g1b = (const float*)d_in[9];    p.b1b = (const float*)d_in[10];
  p.m1b = (const float*)d_in[11];   p.v1b = (const float*)d_in[12];
  p.c2a_w = (const float*)d_in[13]; p.c2a_b = (const float*)d_in[14];
  p.g2a = (const float*)d_in[15];   p.b2a = (const float*)d_in[16];
  p.m2a = (const float*)d_in[17];   p.v2a = (const float*)d_in[18];
  p.c2b_w = (const float*)d_in[19]; p.c2b_b = (const float*)d_in[20];
  p.g2b = (const float*)d_in[21];   p.b2b = (const float*)d_in[22];
  p.m2b = (const float*)d_in[23];   p.v2b = (const float*)d_in[24];
  for (int i = 0; i < 3; ++i) {
    p.qw[i] = (const float*)d_in[25 + 4 * i];
    p.qb[i] = (const float*)d_in[26 + 4 * i];
    p.rw[i] = (const float*)d_in[27 + 4 * i];
    p.rb[i] = (const float*)d_in[28 + 4 * i];
  }
  p.wih = (const float*)d_in[37]; p.whh = (const float*)d_in[38];
  p.bih = (const float*)d_in[39]; p.bhh = (const float*)d_in[40];
  p.fcw = (const float*)d_in[41]; p.fcb = (const float*)d_in[42];
  float* out = (float*)d_out;
  char* base = (char*)d_ws;

  // z elems = 67,108,864 ; y1 elems = 33,554,432 ; stats block = 6,422,528 B
  const size_t ZB_F32 = 268435456, ZB_BF16 = 134217728, Y1B = 67108864;
  const size_t STATS = 1048576 * 2 + 65536 + 2097152 * 2 + 65536;
  const size_t HI_NEED = ZB_F32 + Y1B + STATS;   // ~326 MiB
  const size_t LO_NEED = ZB_BF16 + Y1B + STATS;  // ~198 MiB

  if (ws_size >= HI_NEED) {
    float* z = (float*)base;
    u16* y1u = (u16*)(base + ZB_F32);
    float* scr = (float*)(base + ZB_F32);  // overlays y1u after conv2 is done
    char* sb = base + ZB_F32 + Y1B;
    run_all<float>(p, z, y1u, scr,
                   (float*)sb, (float*)(sb + 1048576), (float*)(sb + 2097152),
                   (float*)(sb + 2162688), (float*)(sb + 4259840),
                   (float*)(sb + 6356992), out, stream);
  } else if (ws_size >= LO_NEED) {
    u16* z = (u16*)base;
    u16* y1u = (u16*)(base + ZB_BF16);
    float* scr = (float*)(base + ZB_BF16);  // overlays y1u after conv2 is done
    char* sb = base + ZB_BF16 + Y1B;
    run_all<u16>(p, z, y1u, scr,
                 (float*)sb, (float*)(sb + 1048576), (float*)(sb + 2097152),
                 (float*)(sb + 2162688), (float*)(sb + 4259840),
                 (float*)(sb + 6356992), out, stream);
  } else {
    k_report<<<3, 256, 0, stream>>>(out, (float)(ws_size >> 20), out_size);
  }
}

// Round 6
// 27820.340 us; speedup vs baseline: 2.3757x; 2.3757x over previous
//
#include <hip/hip_runtime.h>
#include <math.h>

// ---------------------------------------------------------------------------
// SimAM-CNN + Mogrifier-LSTM (Round 8): back to the PROVEN multi-kernel
// baseline (28.5 ms), with two safe upgrades:
//  1) 12 -> 8 dispatches/step: hmfin fused into the next kernel's LDS fill
//     (bit-exact summation order), k_whh merged into k_g (k_gw).
//  2) f16 weights for q/r/wih/whh matmuls (one-time conversion; ldh4 loads
//     keep the baseline loop structure).
// Persistent-kernel line abandoned: 5 rounds showed XCD coherence + barrier
// traffic always exceeds the ~12us/dispatch it tries to save.
// ---------------------------------------------------------------------------

typedef unsigned short u16;
typedef _Float16 f16;

#define EPSBN 1e-5f

__device__ __forceinline__ float sigf(float x) { return 1.0f / (1.0f + expf(-x)); }

__device__ __forceinline__ float b2f(u16 u) {
  union { unsigned int i; float f; } v; v.i = ((unsigned int)u) << 16; return v.f;
}
__device__ __forceinline__ u16 f2b(float f) {
  union { float f; unsigned int i; } v; v.f = f;
  unsigned int r = v.i + 0x7FFFu + ((v.i >> 16) & 1u);
  return (u16)(r >> 16);
}

template <typename T> __device__ __forceinline__ float ld1(const T* p);
template <> __device__ __forceinline__ float ld1<float>(const float* p) { return *p; }
template <> __device__ __forceinline__ float ld1<u16>(const u16* p) { return b2f(*p); }
template <typename T> __device__ __forceinline__ void st1(T* p, float v);
template <> __device__ __forceinline__ void st1<float>(float* p, float v) { *p = v; }
template <> __device__ __forceinline__ void st1<u16>(u16* p, float v) { *p = f2b(v); }

__device__ __forceinline__ void ldh4(const f16* p, float* w) {
  union { uint2 u; f16 h[4]; } v; v.u = *(const uint2*)p;
#pragma unroll
  for (int i = 0; i < 4; ++i) w[i] = (float)v.h[i];
}

__device__ __forceinline__ float simam_elem(float xv, float s, float ss) {
  float mu = (s - xv) * (1.0f / 8191.0f);
  float var = (ss - xv * xv - 8191.0f * mu * mu) * (1.0f / 8190.0f);
  float einv = ((xv - mu) * (xv - mu) + 2.0f * var + 0.2f) / (4.0f * (var + 0.1f));
  return xv * sigf(einv);
}

// --------------------------- CNN stage 1 (unchanged) -----------------------
__global__ __launch_bounds__(256) void k_conv1(
    const float* __restrict__ x,
    const float* __restrict__ w1a, const float* __restrict__ b1a,
    const float* __restrict__ g1a, const float* __restrict__ bb1a,
    const float* __restrict__ m1a, const float* __restrict__ v1a,
    const float* __restrict__ w1b, const float* __restrict__ b1b,
    const float* __restrict__ g1b, const float* __restrict__ bb1b,
    const float* __restrict__ m1b, const float* __restrict__ v1b,
    u16* __restrict__ y1u, float* __restrict__ ps1, float* __restrict__ pss1)
{
  __shared__ float xs[6][66];
  __shared__ float a1[32][6][66];
  __shared__ float A1[32], T1[32], S2[32], T2[32];
  __shared__ float reds[4][32], redq[4][32];
  const int tid = threadIdx.x;
  const int b = blockIdx.x, t0 = blockIdx.y * 4;
  if (tid < 32) {
    float s = g1a[tid] * rsqrtf(v1a[tid] + EPSBN);
    A1[tid] = w1a[tid] * s;
    T1[tid] = (b1a[tid] - m1a[tid]) * s + bb1a[tid];
    float s2 = g1b[tid] * rsqrtf(v1b[tid] + EPSBN);
    S2[tid] = s2;
    T2[tid] = (b1b[tid] - m1b[tid]) * s2 + bb1b[tid];
  }
  for (int i = tid; i < 6 * 66; i += 256) {
    int r = i / 66, cc = i - r * 66;
    int t = t0 + r - 1, d = cc - 1;
    float v = 0.f;
    if (t >= 0 && t < 128 && d >= 0 && d < 64) v = x[(b * 128 + t) * 64 + d];
    xs[r][cc] = v;
  }
  __syncthreads();
  for (int i = tid; i < 32 * 6 * 66; i += 256) {
    int c = i / 396;
    int rr = i - c * 396;
    int r = rr / 66, cc = rr - r * 66;
    int t = t0 + r - 1, d = cc - 1;
    float v = 0.f;
    if (t >= 0 && t < 128 && d >= 0 && d < 64)
      v = fmaxf(xs[r][cc] * A1[c] + T1[c], 0.f);
    a1[c][r][cc] = v;
  }
  __syncthreads();
  const int d = tid & 63, tq = tid >> 6, lane = tid & 63;
  float acc[32];
#pragma unroll
  for (int i = 0; i < 32; ++i) acc[i] = 0.f;
#pragma unroll 1
  for (int c1 = 0; c1 < 32; ++c1) {
#pragma unroll
    for (int dt = 0; dt < 3; ++dt) {
      float av0 = a1[c1][tq + dt][d];
      float av1 = a1[c1][tq + dt][d + 1];
      float av2 = a1[c1][tq + dt][d + 2];
#pragma unroll
      for (int c2 = 0; c2 < 32; ++c2) {
        const float* wp = w1b + ((c2 * 32 + c1) * 3 + dt) * 3;  // uniform
        acc[c2] += av0 * wp[0] + av1 * wp[1] + av2 * wp[2];
      }
    }
  }
  const size_t ob = (size_t)b * 32 * 8192 + (size_t)(t0 + tq) * 64 + d;
#pragma unroll
  for (int c2 = 0; c2 < 32; ++c2) {
    float v = fmaxf(acc[c2] * S2[c2] + T2[c2], 0.f);
    y1u[ob + (size_t)c2 * 8192] = f2b(v);
    float s = v, q = v * v;
#pragma unroll
    for (int off = 32; off; off >>= 1) {
      s += __shfl_down(s, off);
      q += __shfl_down(q, off);
    }
    if (lane == 0) { reds[tq][c2] = s; redq[tq][c2] = q; }
  }
  __syncthreads();
  if (tid < 32) {
    float s = (reds[0][tid] + reds[1][tid]) + (reds[2][tid] + reds[3][tid]);
    float q = (redq[0][tid] + redq[1][tid]) + (redq[2][tid] + redq[3][tid]);
    ps1[(size_t)((b * 32 + tid) << 5) + blockIdx.y] = s;
    pss1[(size_t)((b * 32 + tid) << 5) + blockIdx.y] = q;
  }
}

__global__ __launch_bounds__(256) void k_red(
    const float* __restrict__ ps, const float* __restrict__ pss,
    float* __restrict__ stats, int npart, int nplanes)
{
  int p = blockIdx.x * 256 + threadIdx.x;
  if (p >= nplanes) return;
  float s = 0.f, q = 0.f;
  for (int j = 0; j < npart; ++j) {
    s += ps[(size_t)p * npart + j];
    q += pss[(size_t)p * npart + j];
  }
  stats[p] = s;
  stats[nplanes + p] = q;
}

template <typename T>
__global__ __launch_bounds__(256) void k_simam_t(
    T* __restrict__ buf, const float* __restrict__ stats, int nplanes)
{
  const int p = blockIdx.x, tid = threadIdx.x;
  T* base = buf + (size_t)p * 8192;
  const float s = stats[p], ss = stats[nplanes + p];
#pragma unroll 4
  for (int i = 0; i < 32; ++i) {
    int idx = tid + i * 256;
    float v = ld1(base + idx);
    st1(base + idx, simam_elem(v, s, ss));
  }
}

// --------------------------- CNN stage 2 (unchanged) -----------------------
template <typename ZT>
__global__ __launch_bounds__(256) void k_conv2(
    const u16* __restrict__ y1u,
    const float* __restrict__ w2a, const float* __restrict__ b2a,
    const float* __restrict__ g2a, const float* __restrict__ bb2a,
    const float* __restrict__ m2a, const float* __restrict__ v2a,
    const float* __restrict__ w2b, const float* __restrict__ b2b,
    const float* __restrict__ g2b, const float* __restrict__ bb2b,
    const float* __restrict__ m2b, const float* __restrict__ v2b,
    ZT* __restrict__ z, float* __restrict__ ps2, float* __restrict__ pss2)
{
  __shared__ float y1s[32][4][66];
  __shared__ float a2[64][4][66];
  __shared__ float sA2a[64], sT2a[64], sA2b[64], sT2b[64];
  const int tid = threadIdx.x;
  const int t0 = blockIdx.x * 2, b = blockIdx.y;
  if (tid < 64) {
    float sa = g2a[tid] * rsqrtf(v2a[tid] + EPSBN);
    sA2a[tid] = sa;
    sT2a[tid] = (b2a[tid] - m2a[tid]) * sa + bb2a[tid];
    float sb = g2b[tid] * rsqrtf(v2b[tid] + EPSBN);
    sA2b[tid] = sb;
    sT2b[tid] = (b2b[tid] - m2b[tid]) * sb + bb2b[tid];
  }
  for (int i = tid; i < 32 * 4 * 66; i += 256) {
    int c1 = i / 264;
    int rr = i - c1 * 264;
    int r = rr / 66, cc = rr - r * 66;
    int t = t0 + r - 1, dd = cc - 1;
    float v = 0.f;
    if (t >= 0 && t < 128 && dd >= 0 && dd < 64)
      v = b2f(y1u[(size_t)(b * 32 + c1) * 8192 + t * 64 + dd]);
    y1s[c1][r][cc] = v;
  }
  __syncthreads();
  const int lane = tid & 63;
  const int c2base = __builtin_amdgcn_readfirstlane((int)(tid >> 6)) * 16;
#pragma unroll 1
  for (int i = 0; i < 16; ++i) {
    const int c2 = c2base + i;
    const float* wp = w2a + c2 * 32;  // uniform
    const float scl = sA2a[c2], off = sT2a[c2];
#pragma unroll 1
    for (int r = 0; r < 4; ++r) {
      for (int cc = lane; cc < 66; cc += 64) {
        float acc = 0.f;
#pragma unroll
        for (int c1 = 0; c1 < 32; ++c1) acc += y1s[c1][r][cc] * wp[c1];
        int t = t0 + r - 1, dd = cc - 1;
        float val = 0.f;
        if (t >= 0 && t < 128 && dd >= 0 && dd < 64)
          val = fmaxf(acc * scl + off, 0.f);
        a2[c2][r][cc] = val;
      }
    }
  }
  __syncthreads();
  const int d = tid & 63;
  const int gq = __builtin_amdgcn_readfirstlane((int)(tid >> 6));
  float acc[16][2];
#pragma unroll
  for (int i = 0; i < 16; ++i) { acc[i][0] = 0.f; acc[i][1] = 0.f; }
#pragma unroll 1
  for (int c1 = 0; c1 < 64; ++c1) {
    float a00 = a2[c1][0][d], a01 = a2[c1][0][d + 1], a02 = a2[c1][0][d + 2];
    float a10 = a2[c1][1][d], a11 = a2[c1][1][d + 1], a12 = a2[c1][1][d + 2];
    float a20 = a2[c1][2][d], a21 = a2[c1][2][d + 1], a22 = a2[c1][2][d + 2];
    float a30 = a2[c1][3][d], a31 = a2[c1][3][d + 1], a32 = a2[c1][3][d + 2];
#pragma unroll
    for (int i = 0; i < 16; ++i) {
      const float* wp = w2b + (size_t)((gq * 16 + i) * 64 + c1) * 9;  // uniform
      float w0 = wp[0], w1 = wp[1], w2 = wp[2];
      float w3 = wp[3], w4 = wp[4], w5 = wp[5];
      float w6 = wp[6], w7 = wp[7], w8 = wp[8];
      acc[i][0] += a00 * w0 + a01 * w1 + a02 * w2 + a10 * w3 + a11 * w4 +
                   a12 * w5 + a20 * w6 + a21 * w7 + a22 * w8;
      acc[i][1] += a10 * w0 + a11 * w1 + a12 * w2 + a20 * w3 + a21 * w4 +
                   a22 * w5 + a30 * w6 + a31 * w7 + a32 * w8;
    }
  }
#pragma unroll
  for (int i = 0; i < 16; ++i) {
    int c2 = gq * 16 + i;
    float sc = sA2b[c2], tb = sT2b[c2];
    float v0 = fmaxf(acc[i][0] * sc + tb, 0.f);
    float v1 = fmaxf(acc[i][1] * sc + tb, 0.f);
    size_t ob = (size_t)(b * 64 + c2) * 8192 + (size_t)t0 * 64 + d;
    st1(z + ob, v0);
    st1(z + ob + 64, v1);
    float s = v0 + v1, q = v0 * v0 + v1 * v1;
#pragma unroll
    for (int off = 32; off; off >>= 1) {
      s += __shfl_down(s, off);
      q += __shfl_down(q, off);
    }
    if (lane == 0) {
      ps2[(size_t)((b * 64 + c2) << 6) + blockIdx.x] = s;
      pss2[(size_t)((b * 64 + c2) << 6) + blockIdx.x] = q;
    }
  }
}

// --------------------- weight conversion (f32 -> f16) ----------------------
__global__ __launch_bounds__(256) void k_w16(const float* __restrict__ s,
                                             f16* __restrict__ d, int n) {
  for (int i = blockIdx.x * 256 + threadIdx.x; i < n; i += gridDim.x * 256)
    d[i] = (f16)s[i];
}

// --------------------------- LSTM kernels ----------------------------------
__global__ __launch_bounds__(256) void k_hfin(
    const float* __restrict__ gslab, const float* __restrict__ bih,
    const float* __restrict__ bhh, float* __restrict__ h, float* __restrict__ c,
    int is_t0)
{
  const int i = blockIdx.x * 256 + threadIdx.x;
  const int b = i >> 8, k = i & 255;
  if (is_t0) { h[i] = 0.f; c[i] = 0.f; return; }
  float gi = bih[k] + bhh[k];
  float gf = bih[k + 256] + bhh[k + 256];
  float gg = bih[k + 512] + bhh[k + 512];
  float go = bih[k + 768] + bhh[k + 768];
#pragma unroll 1
  for (int s = 0; s < 17; ++s) {
    const float* gs = gslab + (size_t)s * 131072 + b * 1024;
    gi += gs[k]; gf += gs[k + 256]; gg += gs[k + 512]; go += gs[k + 768];
  }
  float cn = sigf(gf) * c[i] + sigf(gi) * tanhf(gg);
  c[i] = cn;
  h[i] = sigf(go) * tanhf(cn);
}

// q stage. FUSE=false: hms <- hmsrc (h). FUSE=true: hms <- hmfin(prev) =
// 2*sig(rbv + sum_{ss<8} rslab[ss]) * hmsrc  (bit-exact vs old k_hmfin),
// and blockIdx.x==0 blocks materialize hms -> hmout for later consumers.
// xm[b,n] = 2*sigmoid(hms[b,:] . qW[n,:] + qb[n]) * xin[b,n].
template <typename XT, bool FUSE>
__global__ __launch_bounds__(256) void k_q(
    const f16* __restrict__ qW, const float* __restrict__ qb,
    const float* __restrict__ hmsrc,
    const float* __restrict__ rslab, const float* __restrict__ rbv,
    float* __restrict__ hmout,
    const XT* __restrict__ xin, int xin_bstride, float* __restrict__ xm)
{
  __shared__ float hms[32][256];
  const int tid = threadIdx.x;
  const int n0 = blockIdx.x * 64, b0 = blockIdx.y * 32;
  if (!FUSE) {
    for (int i = tid; i < 32 * 256; i += 256) {
      int bl = i >> 8, k = i & 255;
      hms[bl][k] = hmsrc[(b0 + bl) * 256 + k];
    }
  } else {
    for (int i = tid; i < 2048; i += 256) {  // float4 granularity
      int bl = i >> 6, c4 = (i & 63) << 2;
      int b = b0 + bl;
      float4 acc = *(const float4*)(rbv + c4);
#pragma unroll
      for (int ss = 0; ss < 8; ++ss) {
        float4 rv = *(const float4*)(rslab + (size_t)((ss * 128 + b) << 8) + c4);
        acc.x += rv.x; acc.y += rv.y; acc.z += rv.z; acc.w += rv.w;
      }
      float4 sv = *(const float4*)(hmsrc + (b << 8) + c4);
      float4 o;
      o.x = 2.0f * sigf(acc.x) * sv.x;
      o.y = 2.0f * sigf(acc.y) * sv.y;
      o.z = 2.0f * sigf(acc.z) * sv.z;
      o.w = 2.0f * sigf(acc.w) * sv.w;
      *(float4*)&hms[bl][c4] = o;
    }
  }
  __syncthreads();
  if (FUSE && blockIdx.x == 0) {
    for (int i = tid; i < 8192; i += 256)
      hmout[(b0 << 8) + i] = hms[i >> 8][i & 255];
  }
  const int n = n0 + (tid & 63), bg = tid >> 6;
  float acc[8];
#pragma unroll
  for (int j = 0; j < 8; ++j) acc[j] = 0.f;
  const f16* wrow = qW + (size_t)n * 256;
  for (int k = 0; k < 256; k += 4) {
    float w[4];
    ldh4(wrow + k, w);
#pragma unroll
    for (int j = 0; j < 8; ++j) {
      float4 hv = *(const float4*)&hms[bg * 8 + j][k];
      acc[j] += w[0] * hv.x + w[1] * hv.y + w[2] * hv.z + w[3] * hv.w;
    }
  }
  float bias = qb[n];
#pragma unroll
  for (int j = 0; j < 8; ++j) {
    int b = b0 + bg * 8 + j;
    float xv = ld1(xin + (size_t)b * xin_bstride + n);
    xm[(size_t)b * 4096 + n] = 2.0f * sigf(acc[j] + bias) * xv;
  }
}

__global__ __launch_bounds__(256) void k_r(
    const f16* __restrict__ rW, const float* __restrict__ xm,
    float* __restrict__ rslab)
{
  __shared__ float xms[32][128];
  const int tid = threadIdx.x;
  const int n0 = blockIdx.x * 32, b0 = blockIdx.y * 32, ks = blockIdx.z;
  const int n = n0 + (tid & 31), bg = tid >> 5;
  float acc[4] = {0.f, 0.f, 0.f, 0.f};
  const f16* wrow = rW + (size_t)n * 4096;
#pragma unroll 1
  for (int sub = 0; sub < 4; ++sub) {
    const int kbase = ks * 512 + sub * 128;
    __syncthreads();
    for (int i = tid; i < 1024; i += 256) {
      int row = i >> 5, col4 = i & 31;
      *(float4*)&xms[row][col4 * 4] =
          *(const float4*)(xm + (size_t)(b0 + row) * 4096 + kbase + col4 * 4);
    }
    __syncthreads();
    for (int k = 0; k < 128; k += 4) {
      float w[4];
      ldh4(wrow + kbase + k, w);
#pragma unroll
      for (int j = 0; j < 4; ++j) {
        float4 xv = *(const float4*)&xms[bg * 4 + j][k];
        acc[j] += w[0] * xv.x + w[1] * xv.y + w[2] * xv.z + w[3] * xv.w;
      }
    }
  }
#pragma unroll
  for (int j = 0; j < 4; ++j)
    rslab[(size_t)(ks * 128 + b0 + bg * 4 + j) * 256 + n] = acc[j];
}

// merged gates kernel: grid (4,4,20).
//  ks<16 : wih K-slice (baseline k_g, f16 weights) -> gslab[ks]
//  ks>=16: whh part (nt=(ks-16)*4+bx), with hmfin2 fused into the LDS fill:
//          hm2 = 2*sig(rb2 + sum rslab[ss]) * hmB  -> gslab[16]
__global__ __launch_bounds__(256) void k_gw(
    const f16* __restrict__ wih, const f16* __restrict__ whh,
    const float* __restrict__ xm, const float* __restrict__ rslab,
    const float* __restrict__ rb2, const float* __restrict__ hmB,
    float* __restrict__ gslab)
{
  __shared__ float sm[32 * 256];  // 32 KB shared by both branches
  const int tid = threadIdx.x;
  const int ks = blockIdx.z;
  if (ks < 16) {
    float (*xms)[128] = (float (*)[128])sm;
    const int jt = blockIdx.x, b0 = blockIdx.y * 32;
    const int nj = jt * 64 + (tid & 63), bg = tid >> 6;
    float acc[8][4];
#pragma unroll
    for (int j = 0; j < 8; ++j)
#pragma unroll
      for (int g = 0; g < 4; ++g) acc[j][g] = 0.f;
    const f16* w0 = wih + (size_t)nj * 4096;
    const f16* w1 = wih + (size_t)(nj + 256) * 4096;
    const f16* w2 = wih + (size_t)(nj + 512) * 4096;
    const f16* w3 = wih + (size_t)(nj + 768) * 4096;
#pragma unroll 1
    for (int sub = 0; sub < 2; ++sub) {
      const int kbase = ks * 256 + sub * 128;
      __syncthreads();
      for (int i = tid; i < 1024; i += 256) {
        int row = i >> 5, col4 = i & 31;
        *(float4*)&xms[row][col4 * 4] =
            *(const float4*)(xm + (size_t)(b0 + row) * 4096 + kbase + col4 * 4);
      }
      __syncthreads();
      for (int k = 0; k < 128; k += 4) {
        float wa[4], wb[4], wc[4], wd[4];
        ldh4(w0 + kbase + k, wa);
        ldh4(w1 + kbase + k, wb);
        ldh4(w2 + kbase + k, wc);
        ldh4(w3 + kbase + k, wd);
#pragma unroll
        for (int j = 0; j < 8; ++j) {
          float4 xv = *(const float4*)&xms[bg * 8 + j][k];
          acc[j][0] += wa[0] * xv.x + wa[1] * xv.y + wa[2] * xv.z + wa[3] * xv.w;
          acc[j][1] += wb[0] * xv.x + wb[1] * xv.y + wb[2] * xv.z + wb[3] * xv.w;
          acc[j][2] += wc[0] * xv.x + wc[1] * xv.y + wc[2] * xv.z + wc[3] * xv.w;
          acc[j][3] += wd[0] * xv.x + wd[1] * xv.y + wd[2] * xv.z + wd[3] * xv.w;
        }
      }
    }
#pragma unroll
    for (int j = 0; j < 8; ++j) {
      size_t base = (size_t)ks * 131072 + (size_t)(b0 + bg * 8 + j) * 1024 + nj;
      gslab[base]       = acc[j][0];
      gslab[base + 256] = acc[j][1];
      gslab[base + 512] = acc[j][2];
      gslab[base + 768] = acc[j][3];
    }
  } else {
    float (*hms)[256] = (float (*)[256])sm;
    const int nt = (ks - 16) * 4 + blockIdx.x;  // 0..15
    const int b0 = blockIdx.y * 32;
    for (int i = tid; i < 2048; i += 256) {  // fused hmfin2 (float4)
      int bl = i >> 6, c4 = (i & 63) << 2;
      int b = b0 + bl;
      float4 acc = *(const float4*)(rb2 + c4);
#pragma unroll
      for (int ss = 0; ss < 8; ++ss) {
        float4 rv = *(const float4*)(rslab + (size_t)((ss * 128 + b) << 8) + c4);
        acc.x += rv.x; acc.y += rv.y; acc.z += rv.z; acc.w += rv.w;
      }
      float4 sv = *(const float4*)(hmB + (b << 8) + c4);
      float4 o;
      o.x = 2.0f * sigf(acc.x) * sv.x;
      o.y = 2.0f * sigf(acc.y) * sv.y;
      o.z = 2.0f * sigf(acc.z) * sv.z;
      o.w = 2.0f * sigf(acc.w) * sv.w;
      *(float4*)&hms[bl][c4] = o;
    }
    __syncthreads();
    const int n = nt * 64 + (tid & 63), bg = tid >> 6;
    float acc[8];
#pragma unroll
    for (int j = 0; j < 8; ++j) acc[j] = 0.f;
    const f16* wrow = whh + (size_t)n * 256;
    for (int k = 0; k < 256; k += 4) {
      float w[4];
      ldh4(wrow + k, w);
#pragma unroll
      for (int j = 0; j < 8; ++j) {
        float4 hv = *(const float4*)&hms[bg * 8 + j][k];
        acc[j] += w[0] * hv.x + w[1] * hv.y + w[2] * hv.z + w[3] * hv.w;
      }
    }
#pragma unroll
    for (int j = 0; j < 8; ++j)
      gslab[(size_t)16 * 131072 + (size_t)(b0 + bg * 8 + j) * 1024 + n] = acc[j];
  }
}

__global__ __launch_bounds__(256) void k_fc(
    const float* __restrict__ h, const float* __restrict__ fcw,
    const float* __restrict__ fcb, float* __restrict__ out)
{
  __shared__ float hs[256];
  const int tid = threadIdx.x, b = blockIdx.x;
  hs[tid] = h[b * 256 + tid];
  __syncthreads();
  if (tid < 5) {
    float acc = fcb[tid];
    for (int k = 0; k < 256; ++k) acc += hs[k] * fcw[tid * 256 + k];
    out[b * 5 + tid] = acc;
  }
}

// diagnostic: report ws_size (MiB) through the output if workspace too small
__global__ __launch_bounds__(256) void k_report(float* out, float v, int n) {
  int i = blockIdx.x * 256 + threadIdx.x;
  if (i < n) out[i] = v;
}

// ---------------------------------------------------------------------------
struct Net {
  const float *x;
  const float *c1a_w, *c1a_b, *g1a, *b1a, *m1a, *v1a;
  const float *c1b_w, *c1b_b, *g1b, *b1b, *m1b, *v1b;
  const float *c2a_w, *c2a_b, *g2a, *b2a, *m2a, *v2a;
  const float *c2b_w, *c2b_b, *g2b, *b2b, *m2b, *v2b;
  const float *qw[3], *qb[3], *rw[3], *rb[3];
  const float *wih, *whh, *bih, *bhh, *fcw, *fcb;
};

template <typename ZT>
static void run_all(const Net& p, ZT* z, u16* y1u, float* scr,
                    float* ps1, float* pss1, float* st1v,
                    float* ps2, float* pss2, float* st2v,
                    float* out, hipStream_t stream)
{
  float* xm    = scr;            // 524,288
  float* h     = scr + 524288;   // 32,768
  float* c     = scr + 557056;   // 32,768
  float* hmA   = scr + 589824;   // 32,768
  float* hmB   = scr + 622592;   // 32,768
  float* rslab = scr + 655360;   // 262,144
  float* gslab = scr + 917504;   // 2,228,224 (17 slabs of 131072)
  f16*   wf    = (f16*)(scr + 3145728);  // 10,747,904 halves (~20.5 MB)

  k_conv1<<<dim3(128, 32), 256, 0, stream>>>(p.x, p.c1a_w, p.c1a_b, p.g1a,
      p.b1a, p.m1a, p.v1a, p.c1b_w, p.c1b_b, p.g1b, p.b1b, p.m1b, p.v1b,
      y1u, ps1, pss1);
  k_red<<<16, 256, 0, stream>>>(ps1, pss1, st1v, 32, 4096);
  k_simam_t<u16><<<4096, 256, 0, stream>>>(y1u, st1v, 4096);
  k_conv2<ZT><<<dim3(64, 128), 256, 0, stream>>>(y1u, p.c2a_w, p.c2a_b, p.g2a,
      p.b2a, p.m2a, p.v2a, p.c2b_w, p.c2b_b, p.g2b, p.b2b, p.m2b, p.v2b,
      z, ps2, pss2);
  k_red<<<32, 256, 0, stream>>>(ps2, pss2, st2v, 64, 8192);
  k_simam_t<ZT><<<8192, 256, 0, stream>>>(z, st2v, 8192);

  // f16 weight conversion (wf overlays the y1u region; stream-ordered after
  // the CNN's last y1u use).
  f16* qw0f = wf;
  f16* qw1f = wf + 1048576;
  f16* qw2f = wf + 2097152;
  f16* rw0f = wf + 3145728;
  f16* rw1f = wf + 4194304;
  f16* rw2f = wf + 5242880;
  f16* wihf = wf + 6291456;
  f16* whhf = wf + 10485760;
  k_w16<<<1024, 256, 0, stream>>>(p.qw[0], qw0f, 1048576);
  k_w16<<<1024, 256, 0, stream>>>(p.qw[1], qw1f, 1048576);
  k_w16<<<1024, 256, 0, stream>>>(p.qw[2], qw2f, 1048576);
  k_w16<<<1024, 256, 0, stream>>>(p.rw[0], rw0f, 1048576);
  k_w16<<<1024, 256, 0, stream>>>(p.rw[1], rw1f, 1048576);
  k_w16<<<1024, 256, 0, stream>>>(p.rw[2], rw2f, 1048576);
  k_w16<<<4096, 256, 0, stream>>>(p.wih,   wihf, 4194304);
  k_w16<<<1024, 256, 0, stream>>>(p.whh,   whhf, 262144);

  for (int t = 0; t < 128; ++t) {
    k_hfin<<<128, 256, 0, stream>>>(gslab, p.bih, p.bhh, h, c, t == 0 ? 1 : 0);
    // s=0: hms=h, xin=z
    k_q<ZT, false><<<dim3(64, 4), 256, 0, stream>>>(qw0f, p.qb[0], h,
        nullptr, nullptr, nullptr, z + (size_t)t * 4096, 524288, xm);
    k_r<<<dim3(8, 4, 8), 256, 0, stream>>>(rw0f, xm, rslab);
    // s=1: fused hmfin0 (hm0 = 2sig(rslab+rb0)*h) -> hmA; xin=xm
    k_q<float, true><<<dim3(64, 4), 256, 0, stream>>>(qw1f, p.qb[1], h,
        rslab, p.rb[0], hmA, xm, 4096, xm);
    k_r<<<dim3(8, 4, 8), 256, 0, stream>>>(rw1f, xm, rslab);
    // s=2: fused hmfin1 (hm1 = 2sig(rslab+rb1)*hmA) -> hmB; xin=xm
    k_q<float, true><<<dim3(64, 4), 256, 0, stream>>>(qw2f, p.qb[2], hmA,
        rslab, p.rb[1], hmB, xm, 4096, xm);
    k_r<<<dim3(8, 4, 8), 256, 0, stream>>>(rw2f, xm, rslab);
    // gates: wih (ks<16) + whh with fused hmfin2 (ks>=16)
    k_gw<<<dim3(4, 4, 20), 256, 0, stream>>>(wihf, whhf, xm, rslab,
        p.rb[2], hmB, gslab);
  }
  k_hfin<<<128, 256, 0, stream>>>(gslab, p.bih, p.bhh, h, c, 0);
  k_fc<<<128, 256, 0, stream>>>(h, p.fcw, p.fcb, out);
}

extern "C" void kernel_launch(void* const* d_in, const int* in_sizes, int n_in,
                              void* d_out, int out_size, void* d_ws, size_t ws_size,
                              hipStream_t stream)
{
  (void)in_sizes; (void)n_in;
  Net p;
  p.x = (const float*)d_in[0];
  p.c1a_w = (const float*)d_in[1];  p.c1a_b = (const float*)d_in[2];
  p.g1a = (const float*)d_in[3];    p.b1a = (const float*)d_in[4];
  p.m1a = (const float*)d_in[5];    p.v1a = (const float*)d_in[6];
  p.c1b_w = (const float*)d_in[7];  p.c1b_b = (const float*)d_in[8];
  p.g1b = (const float*)d_in[9];    p.b1b = (const float*)d_in[10];
  p.m1b = (const float*)d_in[11];   p.v1b = (const float*)d_in[12];
  p.c2a_w = (const float*)d_in[13]; p.c2a_b = (const float*)d_in[14];
  p.g2a = (const float*)d_in[15];   p.b2a = (const float*)d_in[16];
  p.m2a = (const float*)d_in[17];   p.v2a = (const float*)d_in[18];
  p.c2b_w = (const float*)d_in[19]; p.c2b_b = (const float*)d_in[20];
  p.g2b = (const float*)d_in[21];   p.b2b = (const float*)d_in[22];
  p.m2b = (const float*)d_in[23];   p.v2b = (const float*)d_in[24];
  for (int i = 0; i < 3; ++i) {
    p.qw[i] = (const float*)d_in[25 + 4 * i];
    p.qb[i] = (const float*)d_in[26 + 4 * i];
    p.rw[i] = (const float*)d_in[27 + 4 * i];
    p.rb[i] = (const float*)d_in[28 + 4 * i];
  }
  p.wih = (const float*)d_in[37]; p.whh = (const float*)d_in[38];
  p.bih = (const float*)d_in[39]; p.bhh = (const float*)d_in[40];
  p.fcw = (const float*)d_in[41]; p.fcb = (const float*)d_in[42];
  float* out = (float*)d_out;
  char* base = (char*)d_ws;

  // z elems = 67,108,864 ; y1 elems = 33,554,432 ; stats block = 6,422,528 B
  const size_t ZB_F32 = 268435456, ZB_BF16 = 134217728, Y1B = 67108864;
  const size_t STATS = 1048576 * 2 + 65536 + 2097152 * 2 + 65536;
  const size_t HI_NEED = ZB_F32 + Y1B + STATS;   // ~326 MiB
  const size_t LO_NEED = ZB_BF16 + Y1B + STATS;  // ~198 MiB

  if (ws_size >= HI_NEED) {
    float* z = (float*)base;
    u16* y1u = (u16*)(base + ZB_F32);
    float* scr = (float*)(base + ZB_F32);  // overlays y1u after conv2 is done
    char* sb = base + ZB_F32 + Y1B;
    run_all<float>(p, z, y1u, scr,
                   (float*)sb, (float*)(sb + 1048576), (float*)(sb + 2097152),
                   (float*)(sb + 2162688), (float*)(sb + 4259840),
                   (float*)(sb + 6356992), out, stream);
  } else if (ws_size >= LO_NEED) {
    u16* z = (u16*)base;
    u16* y1u = (u16*)(base + ZB_BF16);
    float* scr = (float*)(base + ZB_BF16);  // overlays y1u after conv2 is done
    char* sb = base + ZB_BF16 + Y1B;
    run_all<u16>(p, z, y1u, scr,
                 (float*)sb, (float*)(sb + 1048576), (float*)(sb + 2097152),
                 (float*)(sb + 2162688), (float*)(sb + 4259840),
                 (float*)(sb + 6356992), out, stream);
  } else {
    k_report<<<3, 256, 0, stream>>>(out, (float)(ws_size >> 20), out_size);
  }
}